// Round 4
// baseline (686.131 us; speedup 1.0000x reference)
//
#include <hip/hip_runtime.h>
#include <cstddef>

namespace {

constexpr int    Bn   = 8;
constexpr int    Cc   = 64;    // value channels
constexpr int    Cq   = 8;     // q/k channels
constexpr int    Ln   = 256;   // H == W
constexpr size_t HWn  = 65536; // H*W
constexpr size_t NPIX = (size_t)Bn * HWn; // 524288

// workspace layout (byte offsets)
constexpr size_t WT_B = 0;                        // 80*64 fp32 weights (20 KB)
constexpr size_t QH_B = 32768;                    // NPIX*8 bf16 (8 MB)
constexpr size_t QL_B = QH_B + NPIX * 8 * 2;
constexpr size_t KH_B = QL_B + NPIX * 8 * 2;
constexpr size_t KL_B = KH_B + NPIX * 8 * 2;
constexpr size_t VB_B = KL_B + NPIX * 8 * 2;      // NPIX*64 bf16 (64 MB)
constexpr size_t HO_B = VB_B + NPIX * 64 * 2;     // NPIX*64 fp32 (128 MB)
// total ~235 MB

typedef short bf16x8 __attribute__((ext_vector_type(8)));  // 8 bf16 (4 VGPRs)
typedef float f32x16 __attribute__((ext_vector_type(16))); // MFMA 32x32 C/D
typedef unsigned short u16x4 __attribute__((ext_vector_type(4)));

__device__ __forceinline__ unsigned short f2bf(float x) {
  union { float f; unsigned u; } c; c.f = x;
  unsigned u = c.u + 0x7FFFu + ((c.u >> 16) & 1u); // round-to-nearest-even
  return (unsigned short)(u >> 16);
}
__device__ __forceinline__ float bf2f(unsigned short h) {
  union { unsigned u; float f; } c; c.u = ((unsigned)h) << 16;
  return c.f;
}
__device__ __forceinline__ f32x16 zero16() {
  f32x16 z;
#pragma unroll
  for (int i = 0; i < 16; ++i) z[i] = 0.f;
  return z;
}

} // namespace

// K0: pack weights transposed: wt[c*80 + o], o = [q0..7 | k0..7 | v0..63]
__global__ void pack_weights(const float* __restrict__ Wq,
                             const float* __restrict__ Wk,
                             const float* __restrict__ Wv,
                             float* __restrict__ wt) {
  int idx = blockIdx.x * 256 + threadIdx.x;
  if (idx >= 64 * 80) return;
  int c = idx / 80, o = idx % 80;
  float v;
  if (o < 8)       v = Wq[o * 64 + c];
  else if (o < 16) v = Wk[(o - 8) * 64 + c];
  else             v = Wv[(o - 16) * 64 + c];
  wt[idx] = v;
}

// K1: per-pixel 1x1 convs -> split-bf16 q,k and bf16 v.
// launch_bounds(256,3): VGPR cap ~168 so all 80 fp32 accumulators stay
// register-resident (round-3 compiler split the kernel to 44 VGPRs and
// re-read x per o-chunk -> 155us; the FMA work itself is only ~35us).
__global__ __launch_bounds__(256, 3) void qkv_kernel(
    const float* __restrict__ x, const float* __restrict__ wt,
    const float* __restrict__ bq, const float* __restrict__ bk,
    const float* __restrict__ bv,
    unsigned short* __restrict__ qh, unsigned short* __restrict__ ql,
    unsigned short* __restrict__ kh, unsigned short* __restrict__ kl,
    unsigned short* __restrict__ vb) {
  size_t p = (size_t)blockIdx.x * 256 + threadIdx.x; // 0..524287
  int b = (int)(p >> 16);
  int rem = (int)(p & 65535);
  const float* xb = x + (size_t)b * 64 * HWn + rem;

  float accq[8], acck[8], accv[64];
#pragma unroll
  for (int o = 0; o < 8; ++o) { accq[o] = bq[o]; acck[o] = bk[o]; }
#pragma unroll
  for (int o = 0; o < 64; ++o) accv[o] = bv[o];

#pragma unroll 1
  for (int c0 = 0; c0 < 64; c0 += 8) {
    float xv[8];
#pragma unroll
    for (int cc = 0; cc < 8; ++cc) xv[cc] = xb[(size_t)(c0 + cc) * HWn];
#pragma unroll
    for (int cc = 0; cc < 8; ++cc) {
      const float* w = wt + (c0 + cc) * 80; // wave-uniform -> s_load
      const float xc = xv[cc];
#pragma unroll
      for (int o = 0; o < 8; ++o) accq[o] = fmaf(xc, w[o], accq[o]);
#pragma unroll
      for (int o = 0; o < 8; ++o) acck[o] = fmaf(xc, w[8 + o], acck[o]);
#pragma unroll
      for (int o = 0; o < 64; ++o) accv[o] = fmaf(xc, w[16 + o], accv[o]);
    }
  }

  // q,k: split hi/lo bf16, one uint4 (8 bf16) per tensor per pixel
  {
    unsigned h8[8], l8[8];
#pragma unroll
    for (int o = 0; o < 8; ++o) {
      h8[o] = f2bf(accq[o]);
      l8[o] = f2bf(accq[o] - bf2f((unsigned short)h8[o]));
    }
    uint4 ph = make_uint4(h8[0] | (h8[1] << 16), h8[2] | (h8[3] << 16),
                          h8[4] | (h8[5] << 16), h8[6] | (h8[7] << 16));
    uint4 pl = make_uint4(l8[0] | (l8[1] << 16), l8[2] | (l8[3] << 16),
                          l8[4] | (l8[5] << 16), l8[6] | (l8[7] << 16));
    *(uint4*)(qh + p * 8) = ph;
    *(uint4*)(ql + p * 8) = pl;
  }
  {
    unsigned h8[8], l8[8];
#pragma unroll
    for (int o = 0; o < 8; ++o) {
      h8[o] = f2bf(acck[o]);
      l8[o] = f2bf(acck[o] - bf2f((unsigned short)h8[o]));
    }
    uint4 ph = make_uint4(h8[0] | (h8[1] << 16), h8[2] | (h8[3] << 16),
                          h8[4] | (h8[5] << 16), h8[6] | (h8[7] << 16));
    uint4 pl = make_uint4(l8[0] | (l8[1] << 16), l8[2] | (l8[3] << 16),
                          l8[4] | (l8[5] << 16), l8[6] | (l8[7] << 16));
    *(uint4*)(kh + p * 8) = ph;
    *(uint4*)(kl + p * 8) = pl;
  }
  // v: bf16, 8x uint4
#pragma unroll
  for (int o8 = 0; o8 < 8; ++o8) {
    unsigned e[8];
#pragma unroll
    for (int u = 0; u < 8; ++u) e[u] = f2bf(accv[o8 * 8 + u]);
    uint4 pk = make_uint4(e[0] | (e[1] << 16), e[2] | (e[3] << 16),
                          e[4] | (e[5] << 16), e[6] | (e[7] << 16));
    *(uint4*)(vb + p * 64 + o8 * 8) = pk;
  }
}

// K2: criss-cross attention slice via bf16 MFMA (split hi/lo for S accuracy).
//   S[i,j] = sum_c Q[i,c]K[j,c] (no max-sub; |S|<=42 so exp is fp32-safe)
//   Z_i = sum_j exp(S[i,j]);  Out[c,j] = sum_i (V[c,i]/Z_i) * exp(S[i,j])
// Inputs arrive pre-split bf16 (qh/ql/kh/kl) and bf16 v.
// MODE 0: slice=(b,h) over w, out -> d_out natural. MODE 1: slice=(b,w) over h,
// out -> ho[b][w][c][h].
template <int MODE>
__global__ __launch_bounds__(256) void attn_kernel(
    const unsigned short* __restrict__ qh, const unsigned short* __restrict__ ql,
    const unsigned short* __restrict__ kh, const unsigned short* __restrict__ kl,
    const unsigned short* __restrict__ vb, float* __restrict__ o) {
  const int s = blockIdx.x;  // 0..2047
  const int t = threadIdx.x; // 0..255
  const int b = s >> 8;
  const int r = s & 255;     // h (row mode) or w (col mode)
  const int w = t >> 6;      // wave 0..3
  const int l = t & 63;      // lane
  const int g = l >> 5;      // lane half
  const int ln = l & 31;

  __shared__ short qs_h[256 * 8], qs_l[256 * 8]; // Q split bf16 [row][8]
  __shared__ short ks_h[256 * 8], ks_l[256 * 8]; // K split bf16
  __shared__ short vz[16384];                    // V*(1/Z) bf16, A-frag layout
  __shared__ float Zl[256];                      // Z then 1/Z

  size_t qkb, qk_stride, v_base, v_stride; // short-element offsets
  if (MODE == 0) {
    qkb    = (size_t)s * (Ln * Cq);  qk_stride = Cq;
    v_base = (size_t)s * (Ln * Cc);  v_stride  = Cc;
  } else {
    qkb    = ((size_t)b * HWn + r) * Cq;  qk_stride = (size_t)Ln * Cq;
    v_base = ((size_t)b * HWn + r) * Cc;  v_stride  = (size_t)Ln * Cc;
  }

  // ---- Phase A: stage pre-split Q,K rows (16 B copies, no cvt) ----
  {
    const size_t off = qkb + (size_t)t * qk_stride;
    *(bf16x8*)&qs_h[t * 8] = *(const bf16x8*)(qh + off);
    *(bf16x8*)&qs_l[t * 8] = *(const bf16x8*)(ql + off);
    *(bf16x8*)&ks_h[t * 8] = *(const bf16x8*)(kh + off);
    *(bf16x8*)&ks_l[t * 8] = *(const bf16x8*)(kl + off);
  }
  Zl[t] = 0.f;
  __syncthreads();

  // ---- Phase B (sweep 1): St[j][i] tiles; Z_i row sums ----
  {
    const short* kb = g ? ks_l : ks_h;
    bf16x8 afk0 = *(const bf16x8*)&kb[(ln + 32 * (2 * w + 0)) * 8];
    bf16x8 afk1 = *(const bf16x8*)&kb[(ln + 32 * (2 * w + 1)) * 8];
#pragma unroll 1
    for (int it = 0; it < 8; ++it) {
      int i = ln + 32 * it;
      bf16x8 bh = *(const bf16x8*)&qs_h[i * 8];
      bf16x8 bl = *(const bf16x8*)&qs_l[i * 8];
      float zp = 0.f;
      {
        f32x16 c = zero16();
        c = __builtin_amdgcn_mfma_f32_32x32x16_bf16(afk0, bh, c, 0, 0, 0);
        c = __builtin_amdgcn_mfma_f32_32x32x16_bf16(afk0, bl, c, 0, 0, 0);
#pragma unroll
        for (int rr = 0; rr < 16; ++rr) zp += __expf(c[rr]);
      }
      {
        f32x16 c = zero16();
        c = __builtin_amdgcn_mfma_f32_32x32x16_bf16(afk1, bh, c, 0, 0, 0);
        c = __builtin_amdgcn_mfma_f32_32x32x16_bf16(afk1, bl, c, 0, 0, 0);
#pragma unroll
        for (int rr = 0; rr < 16; ++rr) zp += __expf(c[rr]);
      }
      atomicAdd(&Zl[i], zp);
    }
  }
  __syncthreads();
  Zl[t] = 1.0f / Zl[t];
  __syncthreads();

  // ---- Phase C: stage V * (1/Z_i) bf16 into permuted A-frag layout ----
  // i = 16*sg + 8*a + 4*g2 + t0 ; frag slot ((sg*2+mt)*64 + 32*g2 + (c&31))*8 + 4*a+t0
#pragma unroll 1
  for (int rnd = 0; rnd < 16; ++rnd) {
    int idx = rnd * 256 + t;
    int i = idx >> 4;
    int c4 = (idx & 15) << 2;
    const unsigned short* vp = vb + v_base + (size_t)i * v_stride + c4;
    u16x4 raw = *(const u16x4*)vp;
    float iz = Zl[i];
    int sg = i >> 4, rem = i & 15;
    int a = rem >> 3, g2 = (rem >> 2) & 1, t0 = rem & 3;
    int e = 4 * a + t0;
#pragma unroll
    for (int u = 0; u < 4; ++u) {
      int c = c4 + u;
      int lane_s = 32 * g2 + (c & 31);
      int mt = c >> 5;
      vz[((sg * 2 + mt) * 64 + lane_s) * 8 + e] =
          (short)f2bf(bf2f(raw[u]) * iz);
    }
  }
  __syncthreads();

  // ---- Phase D (sweep 2): S[i][j] tiles -> P bf16 B-frags -> PV MFMA ----
  f32x16 acc00 = zero16(), acc01 = zero16(), acc10 = zero16(), acc11 = zero16();
  {
    bf16x8 bkh[2], bkl[2];
#pragma unroll
    for (int nt2 = 0; nt2 < 2; ++nt2) {
      int j = ln + 32 * (2 * w + nt2);
      bkh[nt2] = *(const bf16x8*)&ks_h[j * 8];
      bkl[nt2] = *(const bf16x8*)&ks_l[j * 8];
    }
    const short* qb = g ? qs_l : qs_h;
#pragma unroll 1
    for (int it = 0; it < 8; ++it) {
      int i = ln + 32 * it;
      bf16x8 aQ = *(const bf16x8*)&qb[i * 8];
      bf16x8 pf[2][2]; // [nt2][s2]
#pragma unroll
      for (int nt2 = 0; nt2 < 2; ++nt2) {
        f32x16 c = zero16();
        c = __builtin_amdgcn_mfma_f32_32x32x16_bf16(aQ, bkh[nt2], c, 0, 0, 0);
        c = __builtin_amdgcn_mfma_f32_32x32x16_bf16(aQ, bkl[nt2], c, 0, 0, 0);
#pragma unroll
        for (int rr = 0; rr < 8; ++rr)
          pf[nt2][0][rr] = (short)f2bf(__expf(c[rr]));
#pragma unroll
        for (int rr = 0; rr < 8; ++rr)
          pf[nt2][1][rr] = (short)f2bf(__expf(c[8 + rr]));
      }
#pragma unroll
      for (int s2 = 0; s2 < 2; ++s2) {
#pragma unroll
        for (int mt = 0; mt < 2; ++mt) {
          bf16x8 vf = *(const bf16x8*)&vz[(((it * 2 + s2) * 2 + mt) * 64 + l) * 8];
          if (mt == 0) {
            acc00 = __builtin_amdgcn_mfma_f32_32x32x16_bf16(vf, pf[0][s2], acc00, 0, 0, 0);
            acc10 = __builtin_amdgcn_mfma_f32_32x32x16_bf16(vf, pf[1][s2], acc10, 0, 0, 0);
          } else {
            acc01 = __builtin_amdgcn_mfma_f32_32x32x16_bf16(vf, pf[0][s2], acc01, 0, 0, 0);
            acc11 = __builtin_amdgcn_mfma_f32_32x32x16_bf16(vf, pf[1][s2], acc11, 0, 0, 0);
          }
        }
      }
    }
  }

  // ---- Phase E: store C-layout accs ----
  // row c = (reg&3) + 8*(reg>>2) + 4*g + 32*mt ; col j = ln + 32*(2w+nt2)
#pragma unroll
  for (int nt2 = 0; nt2 < 2; ++nt2) {
    int j = ln + 32 * (2 * w + nt2);
#pragma unroll
    for (int mt = 0; mt < 2; ++mt) {
      const f32x16& A = (nt2 == 0) ? (mt == 0 ? acc00 : acc01)
                                   : (mt == 0 ? acc10 : acc11);
#pragma unroll
      for (int reg = 0; reg < 16; ++reg) {
        int c = (reg & 3) + 8 * (reg >> 2) + 4 * g + 32 * mt;
        if (MODE == 0) {
          o[((size_t)b * 64 + c) * HWn + (size_t)r * 256 + j] = A[reg];
        } else {
          o[((size_t)s * 64 + c) * 256 + j] = A[reg];
        }
      }
    }
  }
}

// K3: out = gamma*(w_out(in d_out) + h_out(transposed from ho)) + x
__global__ __launch_bounds__(256) void merge_kernel(
    const float* __restrict__ wout, const float* __restrict__ ho,
    const float* __restrict__ x, const float* __restrict__ gamma,
    float* __restrict__ out) {
  const int h0 = blockIdx.x * 16;
  const int c = blockIdx.y;
  const int b = blockIdx.z;
  const int t = threadIdx.x;
  __shared__ float lds[256 * 17]; // [w][hh] padded

  const float g = gamma[0];

#pragma unroll
  for (int it = 0; it < 4; ++it) {
    int e = it * 256 + t;       // 0..1023
    int w = e >> 2, q4 = (e & 3) << 2;
    float4 f = *(const float4*)&ho[(((size_t)b * 256 + w) * 64 + c) * 256 + h0 + q4];
    lds[w * 17 + q4 + 0] = f.x;
    lds[w * 17 + q4 + 1] = f.y;
    lds[w * 17 + q4 + 2] = f.z;
    lds[w * 17 + q4 + 3] = f.w;
  }
  __syncthreads();

#pragma unroll
  for (int rr = 0; rr < 16; ++rr) {
    size_t idx = (((size_t)b * 64 + c) * 256 + h0 + rr) * 256 + t;
    out[idx] = g * (wout[idx] + lds[t * 17 + rr]) + x[idx];
  }
}

extern "C" void kernel_launch(void* const* d_in, const int* in_sizes, int n_in,
                              void* d_out, int out_size, void* d_ws, size_t ws_size,
                              hipStream_t stream) {
  const float* x     = (const float*)d_in[0];
  const float* Wq    = (const float*)d_in[1];
  const float* bq    = (const float*)d_in[2];
  const float* Wk    = (const float*)d_in[3];
  const float* bk    = (const float*)d_in[4];
  const float* Wv    = (const float*)d_in[5];
  const float* bv    = (const float*)d_in[6];
  const float* gamma = (const float*)d_in[7];
  float* out = (float*)d_out;
  char*  ws  = (char*)d_ws;

  float*          wt = (float*)(ws + WT_B);
  unsigned short* qh = (unsigned short*)(ws + QH_B);
  unsigned short* ql = (unsigned short*)(ws + QL_B);
  unsigned short* kh = (unsigned short*)(ws + KH_B);
  unsigned short* kl = (unsigned short*)(ws + KL_B);
  unsigned short* vb = (unsigned short*)(ws + VB_B);
  float*          ho = (float*)(ws + HO_B);

  hipLaunchKernelGGL(pack_weights, dim3(20), dim3(256), 0, stream, Wq, Wk, Wv, wt);
  hipLaunchKernelGGL(qkv_kernel, dim3(2048), dim3(256), 0, stream,
                     x, wt, bq, bk, bv, qh, ql, kh, kl, vb);
  hipLaunchKernelGGL((attn_kernel<0>), dim3(2048), dim3(256), 0, stream,
                     qh, ql, kh, kl, vb, out); // row pass -> w_out in d_out
  hipLaunchKernelGGL((attn_kernel<1>), dim3(2048), dim3(256), 0, stream,
                     qh, ql, kh, kl, vb, ho);  // col pass -> h_out in ws
  hipLaunchKernelGGL(merge_kernel, dim3(16, 64, 8), dim3(256), 0, stream,
                     out, ho, x, gamma, out);
}

// Round 5
// 596.703 us; speedup vs baseline: 1.1499x; 1.1499x over previous
//
#include <hip/hip_runtime.h>
#include <cstddef>

namespace {

constexpr int    Bn   = 8;
constexpr int    Cc   = 64;    // value channels
constexpr int    Cq   = 8;     // q/k channels
constexpr int    Ln   = 256;   // H == W
constexpr size_t HWn  = 65536; // H*W
constexpr size_t NPIX = (size_t)Bn * HWn; // 524288

// workspace layout (byte offsets)
constexpr size_t WT_B = 0;                        // 80*64 fp32 weights (20 KB)
constexpr size_t QH_B = 32768;                    // NPIX*8 bf16 (8 MB)
constexpr size_t QL_B = QH_B + NPIX * 8 * 2;
constexpr size_t KH_B = QL_B + NPIX * 8 * 2;
constexpr size_t KL_B = KH_B + NPIX * 8 * 2;
constexpr size_t VB_B = KL_B + NPIX * 8 * 2;      // NPIX*64 bf16 (64 MB)
constexpr size_t HO_B = VB_B + NPIX * 64 * 2;     // NPIX*64 fp32 (128 MB)
// total ~235 MB

typedef short bf16x8 __attribute__((ext_vector_type(8)));  // 8 bf16 (4 VGPRs)
typedef float f32x16 __attribute__((ext_vector_type(16))); // MFMA 32x32 C/D
typedef unsigned short u16x4 __attribute__((ext_vector_type(4)));

__device__ __forceinline__ unsigned short f2bf(float x) {
  union { float f; unsigned u; } c; c.f = x;
  unsigned u = c.u + 0x7FFFu + ((c.u >> 16) & 1u); // round-to-nearest-even
  return (unsigned short)(u >> 16);
}
__device__ __forceinline__ float bf2f(unsigned short h) {
  union { unsigned u; float f; } c; c.u = ((unsigned)h) << 16;
  return c.f;
}
__device__ __forceinline__ f32x16 zero16() {
  f32x16 z;
#pragma unroll
  for (int i = 0; i < 16; ++i) z[i] = 0.f;
  return z;
}

} // namespace

// K0: pack weights transposed: wt[c*80 + o], o = [q0..7 | k0..7 | v0..63]
__global__ void pack_weights(const float* __restrict__ Wq,
                             const float* __restrict__ Wk,
                             const float* __restrict__ Wv,
                             float* __restrict__ wt) {
  int idx = blockIdx.x * 256 + threadIdx.x;
  if (idx >= 64 * 80) return;
  int c = idx / 80, o = idx % 80;
  float v;
  if (o < 8)       v = Wq[o * 64 + c];
  else if (o < 16) v = Wk[(o - 8) * 64 + c];
  else             v = Wv[(o - 16) * 64 + c];
  wt[idx] = v;
}

// K1: per-pixel 1x1 convs, o-dim split across blocks (grid.x = chunk):
//   chunk 0   -> q (split bf16 hi/lo) + k (split bf16 hi/lo)
//   chunk 1-4 -> v channels [16*(chunk-1), 16*chunk) as bf16
// 16 accumulators/thread (rounds 3-4 showed the compiler refuses to hold 80:
// it restructured to 44/68 VGPRs and re-read x -> 155/216us). x is read 5x,
// but chunk-adjacent dispatch order makes 4 of 5 reads L2/L3 hits.
__global__ __launch_bounds__(256) void qkv_kernel(
    const float* __restrict__ x, const float* __restrict__ wt,
    const float* __restrict__ bq, const float* __restrict__ bk,
    const float* __restrict__ bv,
    unsigned short* __restrict__ qh, unsigned short* __restrict__ ql,
    unsigned short* __restrict__ kh, unsigned short* __restrict__ kl,
    unsigned short* __restrict__ vb) {
  const int chunk = blockIdx.x; // 0..4
  size_t p = (size_t)blockIdx.y * 256 + threadIdx.x; // 0..524287
  int b = (int)(p >> 16);
  int rem = (int)(p & 65535);
  const float* xb = x + (size_t)b * 64 * HWn + rem;

  float acc[16];
  if (chunk == 0) {
#pragma unroll
    for (int o = 0; o < 8; ++o) { acc[o] = bq[o]; acc[8 + o] = bk[o]; }
  } else {
#pragma unroll
    for (int o = 0; o < 16; ++o) acc[o] = bv[(chunk - 1) * 16 + o];
  }
  const int woff = (chunk == 0) ? 0 : 16 + (chunk - 1) * 16;

#pragma unroll 1
  for (int c0 = 0; c0 < 64; c0 += 8) {
    float xv[8];
#pragma unroll
    for (int cc = 0; cc < 8; ++cc) xv[cc] = xb[(size_t)(c0 + cc) * HWn];
#pragma unroll
    for (int cc = 0; cc < 8; ++cc) {
      const float* w = wt + (c0 + cc) * 80 + woff; // wave-uniform -> s_load
      const float xc = xv[cc];
#pragma unroll
      for (int o = 0; o < 16; ++o) acc[o] = fmaf(xc, w[o], acc[o]);
    }
  }

  if (chunk == 0) {
    // q = acc[0..7], k = acc[8..15]: split hi/lo bf16
    unsigned h8[16], l8[16];
#pragma unroll
    for (int o = 0; o < 16; ++o) {
      h8[o] = f2bf(acc[o]);
      l8[o] = f2bf(acc[o] - bf2f((unsigned short)h8[o]));
    }
    uint4 pqh = make_uint4(h8[0] | (h8[1] << 16), h8[2] | (h8[3] << 16),
                           h8[4] | (h8[5] << 16), h8[6] | (h8[7] << 16));
    uint4 pql = make_uint4(l8[0] | (l8[1] << 16), l8[2] | (l8[3] << 16),
                           l8[4] | (l8[5] << 16), l8[6] | (l8[7] << 16));
    uint4 pkh = make_uint4(h8[8] | (h8[9] << 16), h8[10] | (h8[11] << 16),
                           h8[12] | (h8[13] << 16), h8[14] | (h8[15] << 16));
    uint4 pkl = make_uint4(l8[8] | (l8[9] << 16), l8[10] | (l8[11] << 16),
                           l8[12] | (l8[13] << 16), l8[14] | (l8[15] << 16));
    *(uint4*)(qh + p * 8) = pqh;
    *(uint4*)(ql + p * 8) = pql;
    *(uint4*)(kh + p * 8) = pkh;
    *(uint4*)(kl + p * 8) = pkl;
  } else {
    unsigned e[16];
#pragma unroll
    for (int u = 0; u < 16; ++u) e[u] = f2bf(acc[u]);
    uint4 p0 = make_uint4(e[0] | (e[1] << 16), e[2] | (e[3] << 16),
                          e[4] | (e[5] << 16), e[6] | (e[7] << 16));
    uint4 p1 = make_uint4(e[8] | (e[9] << 16), e[10] | (e[11] << 16),
                          e[12] | (e[13] << 16), e[14] | (e[15] << 16));
    unsigned short* vp = vb + p * 64 + (size_t)(chunk - 1) * 16;
    *(uint4*)(vp + 0) = p0;
    *(uint4*)(vp + 8) = p1;
  }
}

// K2: criss-cross attention slice via bf16 MFMA (split hi/lo for S accuracy).
//   S[i,j] = sum_c Q[i,c]K[j,c] (no max-sub; |S|<=42 so exp is fp32-safe)
//   Z_i = sum_j exp(S[i,j]);  Out[c,j] = sum_i (V[c,i]/Z_i) * exp(S[i,j])
// Inputs arrive pre-split bf16 (qh/ql/kh/kl) and bf16 v.
// MODE 0: slice=(b,h) over w, out -> d_out natural. MODE 1: slice=(b,w) over h,
// out -> ho[b][w][c][h].
template <int MODE>
__global__ __launch_bounds__(256) void attn_kernel(
    const unsigned short* __restrict__ qh, const unsigned short* __restrict__ ql,
    const unsigned short* __restrict__ kh, const unsigned short* __restrict__ kl,
    const unsigned short* __restrict__ vb, float* __restrict__ o) {
  const int s = blockIdx.x;  // 0..2047
  const int t = threadIdx.x; // 0..255
  const int b = s >> 8;
  const int r = s & 255;     // h (row mode) or w (col mode)
  const int w = t >> 6;      // wave 0..3
  const int l = t & 63;      // lane
  const int g = l >> 5;      // lane half
  const int ln = l & 31;

  __shared__ short qs_h[256 * 8], qs_l[256 * 8]; // Q split bf16 [row][8]
  __shared__ short ks_h[256 * 8], ks_l[256 * 8]; // K split bf16
  __shared__ short vz[16384];                    // V*(1/Z) bf16, A-frag layout
  __shared__ float Zl[256];                      // Z then 1/Z

  size_t qkb, qk_stride, v_base, v_stride; // short-element offsets
  if (MODE == 0) {
    qkb    = (size_t)s * (Ln * Cq);  qk_stride = Cq;
    v_base = (size_t)s * (Ln * Cc);  v_stride  = Cc;
  } else {
    qkb    = ((size_t)b * HWn + r) * Cq;  qk_stride = (size_t)Ln * Cq;
    v_base = ((size_t)b * HWn + r) * Cc;  v_stride  = (size_t)Ln * Cc;
  }

  // ---- Phase A: stage pre-split Q,K rows (16 B copies, no cvt) ----
  {
    const size_t off = qkb + (size_t)t * qk_stride;
    *(bf16x8*)&qs_h[t * 8] = *(const bf16x8*)(qh + off);
    *(bf16x8*)&qs_l[t * 8] = *(const bf16x8*)(ql + off);
    *(bf16x8*)&ks_h[t * 8] = *(const bf16x8*)(kh + off);
    *(bf16x8*)&ks_l[t * 8] = *(const bf16x8*)(kl + off);
  }
  Zl[t] = 0.f;
  __syncthreads();

  // ---- Phase B (sweep 1): St[j][i] tiles; Z_i row sums ----
  {
    const short* kb = g ? ks_l : ks_h;
    bf16x8 afk0 = *(const bf16x8*)&kb[(ln + 32 * (2 * w + 0)) * 8];
    bf16x8 afk1 = *(const bf16x8*)&kb[(ln + 32 * (2 * w + 1)) * 8];
#pragma unroll 1
    for (int it = 0; it < 8; ++it) {
      int i = ln + 32 * it;
      bf16x8 bh = *(const bf16x8*)&qs_h[i * 8];
      bf16x8 bl = *(const bf16x8*)&qs_l[i * 8];
      float zp = 0.f;
      {
        f32x16 c = zero16();
        c = __builtin_amdgcn_mfma_f32_32x32x16_bf16(afk0, bh, c, 0, 0, 0);
        c = __builtin_amdgcn_mfma_f32_32x32x16_bf16(afk0, bl, c, 0, 0, 0);
#pragma unroll
        for (int rr = 0; rr < 16; ++rr) zp += __expf(c[rr]);
      }
      {
        f32x16 c = zero16();
        c = __builtin_amdgcn_mfma_f32_32x32x16_bf16(afk1, bh, c, 0, 0, 0);
        c = __builtin_amdgcn_mfma_f32_32x32x16_bf16(afk1, bl, c, 0, 0, 0);
#pragma unroll
        for (int rr = 0; rr < 16; ++rr) zp += __expf(c[rr]);
      }
      atomicAdd(&Zl[i], zp);
    }
  }
  __syncthreads();
  Zl[t] = 1.0f / Zl[t];
  __syncthreads();

  // ---- Phase C: stage V * (1/Z_i) bf16 into permuted A-frag layout ----
  // i = 16*sg + 8*a + 4*g2 + t0 ; frag slot ((sg*2+mt)*64 + 32*g2 + (c&31))*8 + 4*a+t0
#pragma unroll 1
  for (int rnd = 0; rnd < 16; ++rnd) {
    int idx = rnd * 256 + t;
    int i = idx >> 4;
    int c4 = (idx & 15) << 2;
    const unsigned short* vp = vb + v_base + (size_t)i * v_stride + c4;
    u16x4 raw = *(const u16x4*)vp;
    float iz = Zl[i];
    int sg = i >> 4, rem = i & 15;
    int a = rem >> 3, g2 = (rem >> 2) & 1, t0 = rem & 3;
    int e = 4 * a + t0;
#pragma unroll
    for (int u = 0; u < 4; ++u) {
      int c = c4 + u;
      int lane_s = 32 * g2 + (c & 31);
      int mt = c >> 5;
      vz[((sg * 2 + mt) * 64 + lane_s) * 8 + e] =
          (short)f2bf(bf2f(raw[u]) * iz);
    }
  }
  __syncthreads();

  // ---- Phase D (sweep 2): S[i][j] tiles -> P bf16 B-frags -> PV MFMA ----
  f32x16 acc00 = zero16(), acc01 = zero16(), acc10 = zero16(), acc11 = zero16();
  {
    bf16x8 bkh[2], bkl[2];
#pragma unroll
    for (int nt2 = 0; nt2 < 2; ++nt2) {
      int j = ln + 32 * (2 * w + nt2);
      bkh[nt2] = *(const bf16x8*)&ks_h[j * 8];
      bkl[nt2] = *(const bf16x8*)&ks_l[j * 8];
    }
    const short* qb = g ? qs_l : qs_h;
#pragma unroll 1
    for (int it = 0; it < 8; ++it) {
      int i = ln + 32 * it;
      bf16x8 aQ = *(const bf16x8*)&qb[i * 8];
      bf16x8 pf[2][2]; // [nt2][s2]
#pragma unroll
      for (int nt2 = 0; nt2 < 2; ++nt2) {
        f32x16 c = zero16();
        c = __builtin_amdgcn_mfma_f32_32x32x16_bf16(aQ, bkh[nt2], c, 0, 0, 0);
        c = __builtin_amdgcn_mfma_f32_32x32x16_bf16(aQ, bkl[nt2], c, 0, 0, 0);
#pragma unroll
        for (int rr = 0; rr < 8; ++rr)
          pf[nt2][0][rr] = (short)f2bf(__expf(c[rr]));
#pragma unroll
        for (int rr = 0; rr < 8; ++rr)
          pf[nt2][1][rr] = (short)f2bf(__expf(c[8 + rr]));
      }
#pragma unroll
      for (int s2 = 0; s2 < 2; ++s2) {
#pragma unroll
        for (int mt = 0; mt < 2; ++mt) {
          bf16x8 vf = *(const bf16x8*)&vz[(((it * 2 + s2) * 2 + mt) * 64 + l) * 8];
          if (mt == 0) {
            acc00 = __builtin_amdgcn_mfma_f32_32x32x16_bf16(vf, pf[0][s2], acc00, 0, 0, 0);
            acc10 = __builtin_amdgcn_mfma_f32_32x32x16_bf16(vf, pf[1][s2], acc10, 0, 0, 0);
          } else {
            acc01 = __builtin_amdgcn_mfma_f32_32x32x16_bf16(vf, pf[0][s2], acc01, 0, 0, 0);
            acc11 = __builtin_amdgcn_mfma_f32_32x32x16_bf16(vf, pf[1][s2], acc11, 0, 0, 0);
          }
        }
      }
    }
  }

  // ---- Phase E: store C-layout accs ----
  // row c = (reg&3) + 8*(reg>>2) + 4*g + 32*mt ; col j = ln + 32*(2w+nt2)
#pragma unroll
  for (int nt2 = 0; nt2 < 2; ++nt2) {
    int j = ln + 32 * (2 * w + nt2);
#pragma unroll
    for (int mt = 0; mt < 2; ++mt) {
      const f32x16& A = (nt2 == 0) ? (mt == 0 ? acc00 : acc01)
                                   : (mt == 0 ? acc10 : acc11);
#pragma unroll
      for (int reg = 0; reg < 16; ++reg) {
        int c = (reg & 3) + 8 * (reg >> 2) + 4 * g + 32 * mt;
        if (MODE == 0) {
          o[((size_t)b * 64 + c) * HWn + (size_t)r * 256 + j] = A[reg];
        } else {
          o[((size_t)s * 64 + c) * 256 + j] = A[reg];
        }
      }
    }
  }
}

// K3: out = gamma*(w_out(in d_out) + h_out(transposed from ho)) + x
__global__ __launch_bounds__(256) void merge_kernel(
    const float* __restrict__ wout, const float* __restrict__ ho,
    const float* __restrict__ x, const float* __restrict__ gamma,
    float* __restrict__ out) {
  const int h0 = blockIdx.x * 16;
  const int c = blockIdx.y;
  const int b = blockIdx.z;
  const int t = threadIdx.x;
  __shared__ float lds[256 * 17]; // [w][hh] padded

  const float g = gamma[0];

#pragma unroll
  for (int it = 0; it < 4; ++it) {
    int e = it * 256 + t;       // 0..1023
    int w = e >> 2, q4 = (e & 3) << 2;
    float4 f = *(const float4*)&ho[(((size_t)b * 256 + w) * 64 + c) * 256 + h0 + q4];
    lds[w * 17 + q4 + 0] = f.x;
    lds[w * 17 + q4 + 1] = f.y;
    lds[w * 17 + q4 + 2] = f.z;
    lds[w * 17 + q4 + 3] = f.w;
  }
  __syncthreads();

#pragma unroll
  for (int rr = 0; rr < 16; ++rr) {
    size_t idx = (((size_t)b * 64 + c) * 256 + h0 + rr) * 256 + t;
    out[idx] = g * (wout[idx] + lds[t * 17 + rr]) + x[idx];
  }
}

extern "C" void kernel_launch(void* const* d_in, const int* in_sizes, int n_in,
                              void* d_out, int out_size, void* d_ws, size_t ws_size,
                              hipStream_t stream) {
  const float* x     = (const float*)d_in[0];
  const float* Wq    = (const float*)d_in[1];
  const float* bq    = (const float*)d_in[2];
  const float* Wk    = (const float*)d_in[3];
  const float* bk    = (const float*)d_in[4];
  const float* Wv    = (const float*)d_in[5];
  const float* bv    = (const float*)d_in[6];
  const float* gamma = (const float*)d_in[7];
  float* out = (float*)d_out;
  char*  ws  = (char*)d_ws;

  float*          wt = (float*)(ws + WT_B);
  unsigned short* qh = (unsigned short*)(ws + QH_B);
  unsigned short* ql = (unsigned short*)(ws + QL_B);
  unsigned short* kh = (unsigned short*)(ws + KH_B);
  unsigned short* kl = (unsigned short*)(ws + KL_B);
  unsigned short* vb = (unsigned short*)(ws + VB_B);
  float*          ho = (float*)(ws + HO_B);

  hipLaunchKernelGGL(pack_weights, dim3(20), dim3(256), 0, stream, Wq, Wk, Wv, wt);
  hipLaunchKernelGGL(qkv_kernel, dim3(5, 2048), dim3(256), 0, stream,
                     x, wt, bq, bk, bv, qh, ql, kh, kl, vb);
  hipLaunchKernelGGL((attn_kernel<0>), dim3(2048), dim3(256), 0, stream,
                     qh, ql, kh, kl, vb, out); // row pass -> w_out in d_out
  hipLaunchKernelGGL((attn_kernel<1>), dim3(2048), dim3(256), 0, stream,
                     qh, ql, kh, kl, vb, ho);  // col pass -> h_out in ws
  hipLaunchKernelGGL(merge_kernel, dim3(16, 64, 8), dim3(256), 0, stream,
                     out, ho, x, gamma, out);
}